// Round 10
// baseline (1470.889 us; speedup 1.0000x reference)
//
#include <hip/hip_runtime.h>
#include <hip/hip_bf16.h>

#define NN 8192
#define FF 512
#define HH 512
#define CC 64
#define NS_TOTAL 557056     // 512*512 + 512*512 + 64*512
#define KSEL 278529u        // 1 + round(0.5 * (557056-1))
#define MAXNBR 96
#define NBLK 512            // 2 blocks/CU x 256 CUs -- co-residency guaranteed

typedef short short8 __attribute__((ext_vector_type(8)));
typedef __bf16 bf16x8 __attribute__((ext_vector_type(8)));
typedef float f32x4 __attribute__((ext_vector_type(4)));

struct Prm {
    const float *x, *adj, *W0, *W1, *W2, *S0, *S1, *S2;
    float* out;
    unsigned* bar;      // [0]=cnt [1]=gen [2]=degQ_A [3]=degQ_B
    unsigned* hists; float* colsum; float* stats;
    int* nnz; int* colsI; float* dis;
    unsigned short *xh, *xl, *W0h, *W0l, *W1h, *W1l, *W2h, *W2l;
    unsigned short *hAh, *hAl; float *hB, *hAgg;
    unsigned short *hBh, *hBl; float* h3;
};

__device__ inline unsigned short f2bf(float f) {   // RNE f32 -> bf16 bits
    unsigned u = __float_as_uint(f);
    u += 0x7fffu + ((u >> 16) & 1u);
    return (unsigned short)(u >> 16);
}
__device__ inline float bf2f(unsigned short h) {
    return __uint_as_float(((unsigned)h) << 16);
}

__device__ inline f32x4 mfma16x16x32(short8 a, short8 b, f32x4 c) {
    return __builtin_amdgcn_mfma_f32_16x16x32_bf16(
        __builtin_bit_cast(bf16x8, a), __builtin_bit_cast(bf16x8, b), c, 0, 0, 0);
}

__device__ inline void gload_lds16(const unsigned short* g, unsigned short* l) {
    __builtin_amdgcn_global_load_lds(
        (const __attribute__((address_space(1))) void*)g,
        (__attribute__((address_space(3))) void*)l,
        16, 0, 0);
}

// ---- software grid barrier (sense-reversing, device-scope). Safe: grid=2 blocks/CU. ----
__device__ inline void gsync(unsigned* bar) {
    __syncthreads();
    if (threadIdx.x == 0) {
        __threadfence();   // publish this block's prior writes device-wide
        unsigned gen = __hip_atomic_load(bar + 1, __ATOMIC_RELAXED, __HIP_MEMORY_SCOPE_AGENT);
        unsigned a = __hip_atomic_fetch_add(bar, 1u, __ATOMIC_ACQ_REL, __HIP_MEMORY_SCOPE_AGENT);
        if (a == NBLK - 1) {
            __hip_atomic_store(bar, 0u, __ATOMIC_RELAXED, __HIP_MEMORY_SCOPE_AGENT);
            __hip_atomic_fetch_add(bar + 1, 1u, __ATOMIC_RELEASE, __HIP_MEMORY_SCOPE_AGENT);
        } else {
            while (__hip_atomic_load(bar + 1, __ATOMIC_ACQUIRE, __HIP_MEMORY_SCOPE_AGENT) == gen)
                __builtin_amdgcn_s_sleep(2);
        }
        __threadfence();
    }
    __syncthreads();
}

// ---- in-block select via parallel scan; result broadcast to block ----
__device__ void isel(unsigned* smemU, const unsigned* __restrict__ hist, unsigned k,
                     unsigned& bin, unsigned& krem) {
    unsigned* sh = smemU;
    unsigned* res = smemU + 256;
    const int t = threadIdx.x;
    __syncthreads();
    unsigned cnt = hist[t];
    sh[t] = cnt;
    __syncthreads();
#pragma unroll
    for (int off = 1; off < 256; off <<= 1) {
        unsigned u = (t >= off) ? sh[t - off] : 0u;
        __syncthreads();
        sh[t] += u;
        __syncthreads();
    }
    unsigned inc = sh[t], exc = inc - cnt;
    if (exc < k && k <= inc) { res[0] = (unsigned)t; res[1] = k - exc; }
    __syncthreads();
    bin = res[0]; krem = res[1];
}

__device__ void isel_chain(unsigned* smemU, const unsigned* __restrict__ hists, int npass,
                           unsigned& prefix, unsigned& k) {
    prefix = 0; k = KSEL;
    for (int p = 0; p < npass; ++p) {
        unsigned bin, krem;
        isel(smemU, hists + p * 256, k, bin, krem);
        prefix |= bin << (24 - 8 * p);
        k = krem;
    }
}

// ---- deg: one adjacency row (full 256-thread block); smem = scratch for count ----
__device__ void deg_row(const Prm& p, int row, unsigned char* smem) {
    int* dcnt = (int*)smem;
    const int t = threadIdx.x;
    __syncthreads();
    if (t == 0) *dcnt = 0;
    __syncthreads();
    const float4* arow = (const float4*)(p.adj + (size_t)row * NN);
    int* cp = p.colsI + (size_t)row * MAXNBR;
    for (int c4 = t; c4 < NN / 4; c4 += 256) {
        float4 v = arow[c4];
        int base = c4 * 4;
        float vv[4] = {v.x, v.y, v.z, v.w};
#pragma unroll
        for (int kq = 0; kq < 4; ++kq) {
            int col = base + kq;
            if (vv[kq] != 0.f || col == row) {
                int s = atomicAdd(dcnt, 1);
                if (s < MAXNBR) cp[s] = col;
            }
        }
    }
    __syncthreads();
    if (t == 0) {
        int c = *dcnt;
        p.nnz[row] = (c < MAXNBR) ? c : MAXNBR;
        p.dis[row] = rsqrtf((float)c);
    }
    __syncthreads();
}

// ---- work-steal deg rows from an atomic queue ----
__device__ void deg_pool(const Prm& p, unsigned* q, int row0, int count, unsigned char* smem) {
    int* rr = (int*)smem;                 // broadcast slot
    for (;;) {
        __syncthreads();
        if (threadIdx.x == 0) *rr = (int)atomicAdd(q, 1u);
        __syncthreads();
        int r = *rr;
        if (r >= count) break;
        deg_row(p, row0 + r, smem + 16);  // dcnt at smem+16, distinct from rr
    }
}

// ---- hi/lo 3-term MFMA GEMM tile (r8-verified, incl. both-sides swizzle) ----
template<int BMt, int BNt, int WRITE_SPLIT>
__device__ void gemm_tile(const unsigned short* __restrict__ Ah, const unsigned short* __restrict__ Al,
                          const unsigned short* __restrict__ Bh, const unsigned short* __restrict__ Bl,
                          float* __restrict__ Cf, unsigned short* __restrict__ Ch,
                          unsigned short* __restrict__ Cl, int Nn, int bm, int bn,
                          unsigned char* smem) {
    constexpr int BK = 32;
    constexpr int MF = BMt / 32, NF = BNt / 32;
    unsigned short* AhS = (unsigned short*)smem;
    unsigned short* AlS = AhS + BMt * BK;
    unsigned short* BhS = AlS + BMt * BK;
    unsigned short* BlS = BhS + BNt * BK;
    const int tid = threadIdx.x, lane = tid & 63, wid = tid >> 6;
    const int wr = wid >> 1, wc = wid & 1;
    const int r16 = lane & 15, kg = lane >> 4;
    const int srow = lane >> 2;
    const int scol = ((lane & 3) ^ ((srow >> 1) & 3)) * 8;   // pre-swizzled source slot
    constexpr int cA = BMt / 16, cB = BNt / 16, CPW = (2 * cA + 2 * cB) / 4;
    f32x4 acc[MF][NF] = {};

    const int ksw = (kg ^ ((r16 >> 1) & 3)) * 8;             // read-side swizzle
    const unsigned short* pAh = &AhS[(wr * (BMt / 2) + r16) * BK + ksw];
    const unsigned short* pAl = &AlS[(wr * (BMt / 2) + r16) * BK + ksw];
    const unsigned short* pBh = &BhS[(wc * (BNt / 2) + r16) * BK + ksw];
    const unsigned short* pBl = &BlS[(wc * (BNt / 2) + r16) * BK + ksw];

    for (int k0 = 0; k0 < 512; k0 += BK) {
        __syncthreads();
#pragma unroll
        for (int i = 0; i < CPW; ++i) {
            int c = wid * CPW + i;
            const unsigned short* src; unsigned short* dst; int cc, r0;
            if (c < cA)               { src = Ah; dst = AhS; cc = c;               r0 = bm + cc * 16; }
            else if (c < 2 * cA)      { src = Al; dst = AlS; cc = c - cA;          r0 = bm + cc * 16; }
            else if (c < 2 * cA + cB) { src = Bh; dst = BhS; cc = c - 2 * cA;      r0 = bn + cc * 16; }
            else                      { src = Bl; dst = BlS; cc = c - 2 * cA - cB; r0 = bn + cc * 16; }
            gload_lds16(src + (size_t)(r0 + srow) * 512 + k0 + scol, dst + cc * 512);
        }
        __syncthreads();
        short8 bhf[NF], blf[NF];
#pragma unroll
        for (int n = 0; n < NF; ++n) {
            bhf[n] = *(const short8*)(pBh + n * 16 * BK);
            blf[n] = *(const short8*)(pBl + n * 16 * BK);
        }
#pragma unroll
        for (int m = 0; m < MF; ++m) {
            short8 ahf = *(const short8*)(pAh + m * 16 * BK);
            short8 alf = *(const short8*)(pAl + m * 16 * BK);
#pragma unroll
            for (int n = 0; n < NF; ++n) {
                acc[m][n] = mfma16x16x32(ahf, bhf[n], acc[m][n]);
                acc[m][n] = mfma16x16x32(ahf, blf[n], acc[m][n]);
                acc[m][n] = mfma16x16x32(alf, bhf[n], acc[m][n]);
            }
        }
    }
    __syncthreads();   // done with smem before caller reuses it
#pragma unroll
    for (int m = 0; m < MF; ++m) {
#pragma unroll
        for (int n = 0; n < NF; ++n) {
            int row0 = bm + wr * (BMt / 2) + m * 16 + kg * 4;
            int col  = bn + wc * (BNt / 2) + n * 16 + r16;
#pragma unroll
            for (int j = 0; j < 4; ++j) {
                float v = acc[m][n][j];
                if (WRITE_SPLIT) {
                    unsigned short hi = f2bf(v);
                    size_t base = (size_t)(row0 + j) * Nn + col;
                    Ch[base] = hi;
                    Cl[base] = f2bf(v - bf2f(hi));
                } else {
                    Cf[(size_t)(row0 + j) * Nn + col] = v;
                }
            }
        }
    }
}

// ================= the mega-kernel (regular launch + software grid barrier) =================

__global__ __launch_bounds__(256, 2) void mega(Prm p) {
    __shared__ __align__(16) unsigned char SMEM[24 * 1024 + 64];
    unsigned* smemU = (unsigned*)SMEM;
    const int b = blockIdx.x, t = threadIdx.x;

    // ---- P0..P3: radix histogram passes (blocks 0-255) + deg rows 0..1023 ----
    for (int pass = 0; pass < 4; ++pass) {
        if (b < 256) {
            unsigned prefix = 0, k;
            if (pass > 0) isel_chain(smemU, p.hists, pass, prefix, k);
            unsigned pmask = pass ? (0xFFFFFFFFu << (32 - 8 * pass)) : 0u;
            int shift = 24 - 8 * pass;
            unsigned* lh = smemU;
            __syncthreads();
            lh[t] = 0;
            __syncthreads();
            for (int idx = b * 256 + t; idx < NS_TOTAL; idx += 65536) {
                float v = (idx < 262144) ? p.S0[idx]
                        : (idx < 524288) ? p.S1[idx - 262144] : p.S2[idx - 524288];
                unsigned key = __float_as_uint(fabsf(v));
                if ((key & pmask) == prefix)
                    atomicAdd(&lh[(key >> shift) & 0xffu], 1u);
            }
            __syncthreads();
            unsigned c = lh[t];
            if (c) atomicAdd(&p.hists[pass * 256 + t], c);
        } else {
            deg_row(p, pass * 256 + (b - 256), SMEM);
        }
        gsync(p.bar);
    }

    // ---- P4: mask(W->hi/lo) + split(x->hi/lo), grid-stride over 6272 units ----
    {
        unsigned prefix, k;
        isel_chain(smemU, p.hists, 4, prefix, k);
        float thr = __uint_as_float(prefix);
        for (int u = b; u < 6272; u += NBLK) {
            if (u < 2176) {
                int idx = u * 256 + t;    // < NS_TOTAL
                const float* W; const float* S; unsigned short* Yh; unsigned short* Yl; int i;
                if (idx < 262144)      { W = p.W0; S = p.S0; Yh = p.W0h; Yl = p.W0l; i = idx; }
                else if (idx < 524288) { W = p.W1; S = p.S1; Yh = p.W1h; Yl = p.W1l; i = idx - 262144; }
                else                   { W = p.W2; S = p.S2; Yh = p.W2h; Yl = p.W2l; i = idx - 524288; }
                float v = (fabsf(S[i]) > thr) ? W[i] : 0.f;
                unsigned short hi = f2bf(v);
                Yh[i] = hi;
                Yl[i] = f2bf(v - bf2f(hi));
            } else {
                int i = (u - 2176) * 256 + t;   // one float4 of x
                float4 v = ((const float4*)p.x)[i];
                float vv[4] = {v.x, v.y, v.z, v.w};
                ushort4 hi, lo;
                unsigned short* hp = (unsigned short*)&hi;
                unsigned short* lp = (unsigned short*)&lo;
#pragma unroll
                for (int j = 0; j < 4; ++j) {
                    hp[j] = f2bf(vv[j]);
                    lp[j] = f2bf(vv[j] - bf2f(hp[j]));
                }
                *(ushort4*)&p.xh[(size_t)i * 4] = hi;
                *(ushort4*)&p.xl[(size_t)i * 4] = lo;
            }
        }
    }
    gsync(p.bar);

    // ---- P5: gemm1 (512 tiles, one per block) then work-steal deg rows 1024..4607 ----
    gemm_tile<64, 128, 1>(p.xh, p.xl, p.W0h, p.W0l, nullptr, p.hAh, p.hAl,
                          HH, (b >> 2) * 64, (b & 3) * 128, SMEM);
    deg_pool(p, p.bar + 2, 1024, 3584, SMEM);
    gsync(p.bar);

    // ---- P6: gemm2 (512 tiles) then work-steal deg rows 4608..8191 ----
    gemm_tile<64, 128, 0>(p.hAh, p.hAl, p.W1h, p.W1l, p.hB, nullptr, nullptr,
                          HH, (b >> 2) * 64, (b & 3) * 128, SMEM);
    deg_pool(p, p.bar + 3, 4608, 3584, SMEM);
    gsync(p.bar);

    // ---- P7: spmm512  hAgg = adj_n @ hB ----
    for (int base = b * 2; base < NN; base += 2 * NBLK) {
        int row = base + (t >> 7);
        int tt = t & 127;
        int cnt = p.nnz[row];
        const int* cp = p.colsI + (size_t)row * MAXNBR;
        float4 acc = make_float4(0.f, 0.f, 0.f, 0.f);
        for (int j = 0; j < cnt; ++j) {
            int c = cp[j];
            float wgt = p.dis[c];
            float4 v = *(const float4*)(p.hB + (size_t)c * HH + tt * 4);
            acc.x += wgt * v.x; acc.y += wgt * v.y; acc.z += wgt * v.z; acc.w += wgt * v.w;
        }
        float di = p.dis[row];
        acc.x *= di; acc.y *= di; acc.z *= di; acc.w *= di;
        *(float4*)(p.hAgg + (size_t)row * HH + tt * 4) = acc;
    }
    gsync(p.bar);

    // ---- P8: colstats (blocks 0-255): colsum + sum x^2 ----
    if (b < 256) {
        float s0 = 0.f, s1 = 0.f, sq = 0.f;
        for (int r = b; r < NN; r += 256) {
            const float* row = p.hAgg + (size_t)r * HH;
            float a = row[t], c = row[t + 256];
            s0 += a; s1 += c;
            sq += a * a + c * c;
        }
        atomicAdd(&p.colsum[t], s0);
        atomicAdd(&p.colsum[t + 256], s1);
#pragma unroll
        for (int o = 32; o > 0; o >>= 1) sq += __shfl_down(sq, o);
        float* red = (float*)SMEM;
        int wv = t >> 6, lane = t & 63;
        __syncthreads();
        if (lane == 0) red[wv] = sq;
        __syncthreads();
        if (t == 0) atomicAdd(p.stats, red[0] + red[1] + red[2] + red[3]);
    }
    gsync(p.bar);

    // ---- P9: pairnorm apply + relu -> hBh/hBl ----
    {
        const float inv = 1.0f / (float)NN;
        float c0 = p.colsum[t], c1 = p.colsum[t + 256];
        float sq = c0 * c0 + c1 * c1;
#pragma unroll
        for (int o = 32; o > 0; o >>= 1) sq += __shfl_down(sq, o);
        float* red = (float*)SMEM;
        float* sbc = red + 4;
        int wv = t >> 6, lane = t & 63;
        __syncthreads();
        if (lane == 0) red[wv] = sq;
        __syncthreads();
        if (t == 0) {
            float msum = red[0] + red[1] + red[2] + red[3];
            *sbc = 1.0f / sqrtf(1e-6f + (p.stats[0] - msum * inv) * inv);
        }
        __syncthreads();
        float s = *sbc;
        for (int i = b * 256 + t; i < NN * HH / 4; i += NBLK * 256) {
            float4 v = ((const float4*)p.hAgg)[i];
            float4 m = ((const float4*)p.colsum)[i & 127];
            float vv[4];
            vv[0] = fmaxf((v.x - m.x * inv) * s, 0.f);
            vv[1] = fmaxf((v.y - m.y * inv) * s, 0.f);
            vv[2] = fmaxf((v.z - m.z * inv) * s, 0.f);
            vv[3] = fmaxf((v.w - m.w * inv) * s, 0.f);
            ushort4 hi, lo;
            unsigned short* hp = (unsigned short*)&hi;
            unsigned short* lp = (unsigned short*)&lo;
#pragma unroll
            for (int j = 0; j < 4; ++j) {
                hp[j] = f2bf(vv[j]);
                lp[j] = f2bf(vv[j] - bf2f(hp[j]));
            }
            *(ushort4*)&p.hBh[(size_t)i * 4] = hi;
            *(ushort4*)&p.hBl[(size_t)i * 4] = lo;
        }
    }
    gsync(p.bar);

    // ---- P10: gemm3 (256 tiles on blocks 0-255) ----
    if (b < 256)
        gemm_tile<32, 64, 0>(p.hBh, p.hBl, p.W2h, p.W2l, p.h3, nullptr, nullptr,
                             CC, b * 32, 0, SMEM);
    gsync(p.bar);

    // ---- P11: spmm64  out = adj_n @ h3 ----
    for (int base = b * 4; base < NN; base += 4 * NBLK) {
        int row = base + (t >> 6);
        int tt = t & 63;
        int cnt = p.nnz[row];
        const int* cp = p.colsI + (size_t)row * MAXNBR;
        float acc = 0.f;
        for (int j = 0; j < cnt; ++j) {
            int c = cp[j];
            acc += p.dis[c] * p.h3[(size_t)c * CC + tt];
        }
        p.out[(size_t)row * CC + tt] = p.dis[row] * acc;
    }
}

// ---------------- launch ----------------

extern "C" void kernel_launch(void* const* d_in, const int* in_sizes, int n_in,
                              void* d_out, int out_size, void* d_ws, size_t ws_size,
                              hipStream_t stream) {
    char* w = (char*)d_ws;
    size_t off = 0;
    auto alloc = [&](size_t bsz) { size_t r = off; off = (off + bsz + 255) & ~(size_t)255; return r; };

    Prm p;
    p.x   = (const float*)d_in[0];
    p.adj = (const float*)d_in[1];
    p.W0  = (const float*)d_in[2];
    p.W1  = (const float*)d_in[3];
    p.W2  = (const float*)d_in[4];
    p.S0  = (const float*)d_in[5];
    p.S1  = (const float*)d_in[6];
    p.S2  = (const float*)d_in[7];
    p.out = (float*)d_out;

    p.bar    = (unsigned*)(w + alloc(256));            // cnt, gen, degQA, degQB
    p.hists  = (unsigned*)(w + alloc(4 * 256 * 4));
    p.colsum = (float*)(w + alloc(HH * 4));
    p.stats  = (float*)(w + alloc(256));
    size_t zero_end = off;
    p.nnz    = (int*)(w + alloc(NN * 4));
    p.colsI  = (int*)(w + alloc((size_t)NN * MAXNBR * 4));
    p.dis    = (float*)(w + alloc(NN * 4));
    p.xh  = (unsigned short*)(w + alloc((size_t)NN * FF * 2));
    p.xl  = (unsigned short*)(w + alloc((size_t)NN * FF * 2));
    p.W0h = (unsigned short*)(w + alloc((size_t)HH * FF * 2));
    p.W0l = (unsigned short*)(w + alloc((size_t)HH * FF * 2));
    p.W1h = (unsigned short*)(w + alloc((size_t)HH * HH * 2));
    p.W1l = (unsigned short*)(w + alloc((size_t)HH * HH * 2));
    p.W2h = (unsigned short*)(w + alloc((size_t)CC * HH * 2));
    p.W2l = (unsigned short*)(w + alloc((size_t)CC * HH * 2));
    p.hAh = (unsigned short*)(w + alloc((size_t)NN * HH * 2));
    p.hAl = (unsigned short*)(w + alloc((size_t)NN * HH * 2));
    p.hB  = (float*)(w + alloc((size_t)NN * HH * 4));
    p.hAgg= (float*)(w + alloc((size_t)NN * HH * 4));
    p.hBh = (unsigned short*)(w + alloc((size_t)NN * HH * 2));
    p.hBl = (unsigned short*)(w + alloc((size_t)NN * HH * 2));
    p.h3  = (float*)(w + alloc((size_t)NN * CC * 4));
    (void)ws_size; (void)in_sizes; (void)n_in; (void)out_size;

    hipMemsetAsync(d_ws, 0, zero_end, stream);   // zero barrier/queues/hists/colsum/stats
    mega<<<NBLK, 256, 0, stream>>>(p);
}

// Round 11
// 963.146 us; speedup vs baseline: 1.5272x; 1.5272x over previous
//
#include <hip/hip_runtime.h>
#include <hip/hip_bf16.h>

#define NN 8192
#define FF 512
#define HH 512
#define CC 64
#define NS_TOTAL 557056     // 512*512 + 512*512 + 64*512
#define KSEL 278529u        // 1 + round(0.5 * (557056-1))
#define MAXNBR 96
#define NBLK 512            // 2 blocks/CU x 256 CUs -- co-residency guaranteed

typedef short short8 __attribute__((ext_vector_type(8)));
typedef __bf16 bf16x8 __attribute__((ext_vector_type(8)));
typedef float f32x4 __attribute__((ext_vector_type(4)));

struct Prm {
    const float *x, *adj, *W0, *W1, *W2, *S0, *S1, *S2;
    float* out;
    unsigned* bar;      // barrier line: [0]=cnt [1]=gen   (own cacheline)
    unsigned* degq;     // deg queues:   [0]=qA  [1]=qB    (own cacheline)
    unsigned* hists; float* colsum; float* stats;
    int* nnz; int* colsI; float* dis;
    unsigned short *xh, *xl, *W0h, *W0l, *W1h, *W1l, *W2h, *W2l;
    unsigned short *hAh, *hAl; float *hB, *hAgg;
    unsigned short *hBh, *hBl; float* h3;
};

__device__ inline unsigned short f2bf(float f) {   // RNE f32 -> bf16 bits
    unsigned u = __float_as_uint(f);
    u += 0x7fffu + ((u >> 16) & 1u);
    return (unsigned short)(u >> 16);
}
__device__ inline float bf2f(unsigned short h) {
    return __uint_as_float(((unsigned)h) << 16);
}

__device__ inline f32x4 mfma16x16x32(short8 a, short8 b, f32x4 c) {
    return __builtin_amdgcn_mfma_f32_16x16x32_bf16(
        __builtin_bit_cast(bf16x8, a), __builtin_bit_cast(bf16x8, b), c, 0, 0, 0);
}

__device__ inline void gload_lds16(const unsigned short* g, unsigned short* l) {
    __builtin_amdgcn_global_load_lds(
        (const __attribute__((address_space(1))) void*)g,
        (__attribute__((address_space(3))) void*)l,
        16, 0, 0);
}

// ---- software grid barrier, CACHE-SILENT spin ----
// r10 lesson: ACQUIRE agent-scope polls emit an L2 invalidation PER ITERATION on
// multi-XCD -> continuous L2 wipe -> whole kernel latency-bound (1471us). Fix:
// RELAXED polls (sc-bit bypass, no invalidate) + ONE threadfence (acquire) after exit.
__device__ inline void gsync(unsigned* bar) {
    __syncthreads();
    if (threadIdx.x == 0) {
        __threadfence();   // release: prior writes reach coherence point before arrival
        unsigned gen = __hip_atomic_load(bar + 1, __ATOMIC_RELAXED, __HIP_MEMORY_SCOPE_AGENT);
        unsigned a = __hip_atomic_fetch_add(bar, 1u, __ATOMIC_RELAXED, __HIP_MEMORY_SCOPE_AGENT);
        if (a == NBLK - 1) {
            __hip_atomic_store(bar, 0u, __ATOMIC_RELAXED, __HIP_MEMORY_SCOPE_AGENT);
            __hip_atomic_fetch_add(bar + 1, 1u, __ATOMIC_RELAXED, __HIP_MEMORY_SCOPE_AGENT);
        } else {
            while (__hip_atomic_load(bar + 1, __ATOMIC_RELAXED, __HIP_MEMORY_SCOPE_AGENT) == gen)
                __builtin_amdgcn_s_sleep(8);
        }
        __threadfence();   // acquire: invalidate stale cache lines ONCE
    }
    __syncthreads();
}

// ---- in-block select via parallel scan; result broadcast to block ----
__device__ void isel(unsigned* smemU, const unsigned* __restrict__ hist, unsigned k,
                     unsigned& bin, unsigned& krem) {
    unsigned* sh = smemU;
    unsigned* res = smemU + 256;
    const int t = threadIdx.x;
    __syncthreads();
    unsigned cnt = hist[t];
    sh[t] = cnt;
    __syncthreads();
#pragma unroll
    for (int off = 1; off < 256; off <<= 1) {
        unsigned u = (t >= off) ? sh[t - off] : 0u;
        __syncthreads();
        sh[t] += u;
        __syncthreads();
    }
    unsigned inc = sh[t], exc = inc - cnt;
    if (exc < k && k <= inc) { res[0] = (unsigned)t; res[1] = k - exc; }
    __syncthreads();
    bin = res[0]; krem = res[1];
}

__device__ void isel_chain(unsigned* smemU, const unsigned* __restrict__ hists, int npass,
                           unsigned& prefix, unsigned& k) {
    prefix = 0; k = KSEL;
    for (int p = 0; p < npass; ++p) {
        unsigned bin, krem;
        isel(smemU, hists + p * 256, k, bin, krem);
        prefix |= bin << (24 - 8 * p);
        k = krem;
    }
}

// ---- deg: one adjacency row (full 256-thread block); smem = scratch for count ----
__device__ void deg_row(const Prm& p, int row, unsigned char* smem) {
    int* dcnt = (int*)smem;
    const int t = threadIdx.x;
    __syncthreads();
    if (t == 0) *dcnt = 0;
    __syncthreads();
    const float4* arow = (const float4*)(p.adj + (size_t)row * NN);
    int* cp = p.colsI + (size_t)row * MAXNBR;
    for (int c4 = t; c4 < NN / 4; c4 += 256) {
        float4 v = arow[c4];
        int base = c4 * 4;
        float vv[4] = {v.x, v.y, v.z, v.w};
#pragma unroll
        for (int kq = 0; kq < 4; ++kq) {
            int col = base + kq;
            if (vv[kq] != 0.f || col == row) {
                int s = atomicAdd(dcnt, 1);
                if (s < MAXNBR) cp[s] = col;
            }
        }
    }
    __syncthreads();
    if (t == 0) {
        int c = *dcnt;
        p.nnz[row] = (c < MAXNBR) ? c : MAXNBR;
        p.dis[row] = rsqrtf((float)c);
    }
    __syncthreads();
}

// ---- work-steal deg rows from an atomic queue ----
__device__ void deg_pool(const Prm& p, unsigned* q, int row0, int count, unsigned char* smem) {
    int* rr = (int*)smem;                 // broadcast slot
    for (;;) {
        __syncthreads();
        if (threadIdx.x == 0) *rr = (int)atomicAdd(q, 1u);
        __syncthreads();
        int r = *rr;
        if (r >= count) break;
        deg_row(p, row0 + r, smem + 16);  // dcnt at smem+16, distinct from rr
    }
}

// ---- hi/lo 3-term MFMA GEMM tile (r8-verified, incl. both-sides swizzle) ----
template<int BMt, int BNt, int WRITE_SPLIT>
__device__ void gemm_tile(const unsigned short* __restrict__ Ah, const unsigned short* __restrict__ Al,
                          const unsigned short* __restrict__ Bh, const unsigned short* __restrict__ Bl,
                          float* __restrict__ Cf, unsigned short* __restrict__ Ch,
                          unsigned short* __restrict__ Cl, int Nn, int bm, int bn,
                          unsigned char* smem) {
    constexpr int BK = 32;
    constexpr int MF = BMt / 32, NF = BNt / 32;
    unsigned short* AhS = (unsigned short*)smem;
    unsigned short* AlS = AhS + BMt * BK;
    unsigned short* BhS = AlS + BMt * BK;
    unsigned short* BlS = BhS + BNt * BK;
    const int tid = threadIdx.x, lane = tid & 63, wid = tid >> 6;
    const int wr = wid >> 1, wc = wid & 1;
    const int r16 = lane & 15, kg = lane >> 4;
    const int srow = lane >> 2;
    const int scol = ((lane & 3) ^ ((srow >> 1) & 3)) * 8;   // pre-swizzled source slot
    constexpr int cA = BMt / 16, cB = BNt / 16, CPW = (2 * cA + 2 * cB) / 4;
    f32x4 acc[MF][NF] = {};

    const int ksw = (kg ^ ((r16 >> 1) & 3)) * 8;             // read-side swizzle
    const unsigned short* pAh = &AhS[(wr * (BMt / 2) + r16) * BK + ksw];
    const unsigned short* pAl = &AlS[(wr * (BMt / 2) + r16) * BK + ksw];
    const unsigned short* pBh = &BhS[(wc * (BNt / 2) + r16) * BK + ksw];
    const unsigned short* pBl = &BlS[(wc * (BNt / 2) + r16) * BK + ksw];

    for (int k0 = 0; k0 < 512; k0 += BK) {
        __syncthreads();
#pragma unroll
        for (int i = 0; i < CPW; ++i) {
            int c = wid * CPW + i;
            const unsigned short* src; unsigned short* dst; int cc, r0;
            if (c < cA)               { src = Ah; dst = AhS; cc = c;               r0 = bm + cc * 16; }
            else if (c < 2 * cA)      { src = Al; dst = AlS; cc = c - cA;          r0 = bm + cc * 16; }
            else if (c < 2 * cA + cB) { src = Bh; dst = BhS; cc = c - 2 * cA;      r0 = bn + cc * 16; }
            else                      { src = Bl; dst = BlS; cc = c - 2 * cA - cB; r0 = bn + cc * 16; }
            gload_lds16(src + (size_t)(r0 + srow) * 512 + k0 + scol, dst + cc * 512);
        }
        __syncthreads();
        short8 bhf[NF], blf[NF];
#pragma unroll
        for (int n = 0; n < NF; ++n) {
            bhf[n] = *(const short8*)(pBh + n * 16 * BK);
            blf[n] = *(const short8*)(pBl + n * 16 * BK);
        }
#pragma unroll
        for (int m = 0; m < MF; ++m) {
            short8 ahf = *(const short8*)(pAh + m * 16 * BK);
            short8 alf = *(const short8*)(pAl + m * 16 * BK);
#pragma unroll
            for (int n = 0; n < NF; ++n) {
                acc[m][n] = mfma16x16x32(ahf, bhf[n], acc[m][n]);
                acc[m][n] = mfma16x16x32(ahf, blf[n], acc[m][n]);
                acc[m][n] = mfma16x16x32(alf, bhf[n], acc[m][n]);
            }
        }
    }
    __syncthreads();   // done with smem before caller reuses it
#pragma unroll
    for (int m = 0; m < MF; ++m) {
#pragma unroll
        for (int n = 0; n < NF; ++n) {
            int row0 = bm + wr * (BMt / 2) + m * 16 + kg * 4;
            int col  = bn + wc * (BNt / 2) + n * 16 + r16;
#pragma unroll
            for (int j = 0; j < 4; ++j) {
                float v = acc[m][n][j];
                if (WRITE_SPLIT) {
                    unsigned short hi = f2bf(v);
                    size_t base = (size_t)(row0 + j) * Nn + col;
                    Ch[base] = hi;
                    Cl[base] = f2bf(v - bf2f(hi));
                } else {
                    Cf[(size_t)(row0 + j) * Nn + col] = v;
                }
            }
        }
    }
}

// ================= the mega-kernel (regular launch + cache-silent grid barrier) =================

__global__ __launch_bounds__(256, 2) void mega(Prm p) {
    __shared__ __align__(16) unsigned char SMEM[24 * 1024 + 64];
    unsigned* smemU = (unsigned*)SMEM;
    const int b = blockIdx.x, t = threadIdx.x;

    // ---- P0..P3: radix histogram passes (blocks 0-255) + deg rows 0..1023 ----
    for (int pass = 0; pass < 4; ++pass) {
        if (b < 256) {
            unsigned prefix = 0, k;
            if (pass > 0) isel_chain(smemU, p.hists, pass, prefix, k);
            unsigned pmask = pass ? (0xFFFFFFFFu << (32 - 8 * pass)) : 0u;
            int shift = 24 - 8 * pass;
            unsigned* lh = smemU;
            __syncthreads();
            lh[t] = 0;
            __syncthreads();
            for (int idx = b * 256 + t; idx < NS_TOTAL; idx += 65536) {
                float v = (idx < 262144) ? p.S0[idx]
                        : (idx < 524288) ? p.S1[idx - 262144] : p.S2[idx - 524288];
                unsigned key = __float_as_uint(fabsf(v));
                if ((key & pmask) == prefix)
                    atomicAdd(&lh[(key >> shift) & 0xffu], 1u);
            }
            __syncthreads();
            unsigned c = lh[t];
            if (c) atomicAdd(&p.hists[pass * 256 + t], c);
        } else {
            deg_row(p, pass * 256 + (b - 256), SMEM);
        }
        gsync(p.bar);
    }

    // ---- P4: mask(W->hi/lo) + split(x->hi/lo), grid-stride over 6272 units ----
    {
        unsigned prefix, k;
        isel_chain(smemU, p.hists, 4, prefix, k);
        float thr = __uint_as_float(prefix);
        for (int u = b; u < 6272; u += NBLK) {
            if (u < 2176) {
                int idx = u * 256 + t;    // < NS_TOTAL
                const float* W; const float* S; unsigned short* Yh; unsigned short* Yl; int i;
                if (idx < 262144)      { W = p.W0; S = p.S0; Yh = p.W0h; Yl = p.W0l; i = idx; }
                else if (idx < 524288) { W = p.W1; S = p.S1; Yh = p.W1h; Yl = p.W1l; i = idx - 262144; }
                else                   { W = p.W2; S = p.S2; Yh = p.W2h; Yl = p.W2l; i = idx - 524288; }
                float v = (fabsf(S[i]) > thr) ? W[i] : 0.f;
                unsigned short hi = f2bf(v);
                Yh[i] = hi;
                Yl[i] = f2bf(v - bf2f(hi));
            } else {
                int i = (u - 2176) * 256 + t;   // one float4 of x
                float4 v = ((const float4*)p.x)[i];
                float vv[4] = {v.x, v.y, v.z, v.w};
                ushort4 hi, lo;
                unsigned short* hp = (unsigned short*)&hi;
                unsigned short* lp = (unsigned short*)&lo;
#pragma unroll
                for (int j = 0; j < 4; ++j) {
                    hp[j] = f2bf(vv[j]);
                    lp[j] = f2bf(vv[j] - bf2f(hp[j]));
                }
                *(ushort4*)&p.xh[(size_t)i * 4] = hi;
                *(ushort4*)&p.xl[(size_t)i * 4] = lo;
            }
        }
    }
    gsync(p.bar);

    // ---- P5: gemm1 (512 tiles, one per block) then work-steal deg rows 1024..4607 ----
    gemm_tile<64, 128, 1>(p.xh, p.xl, p.W0h, p.W0l, nullptr, p.hAh, p.hAl,
                          HH, (b >> 2) * 64, (b & 3) * 128, SMEM);
    deg_pool(p, p.degq, 1024, 3584, SMEM);
    gsync(p.bar);

    // ---- P6: gemm2 (512 tiles) then work-steal deg rows 4608..8191 ----
    gemm_tile<64, 128, 0>(p.hAh, p.hAl, p.W1h, p.W1l, p.hB, nullptr, nullptr,
                          HH, (b >> 2) * 64, (b & 3) * 128, SMEM);
    deg_pool(p, p.degq + 64, 4608, 3584, SMEM);
    gsync(p.bar);

    // ---- P7: spmm512  hAgg = adj_n @ hB ----
    for (int base = b * 2; base < NN; base += 2 * NBLK) {
        int row = base + (t >> 7);
        int tt = t & 127;
        int cnt = p.nnz[row];
        const int* cp = p.colsI + (size_t)row * MAXNBR;
        float4 acc = make_float4(0.f, 0.f, 0.f, 0.f);
        for (int j = 0; j < cnt; ++j) {
            int c = cp[j];
            float wgt = p.dis[c];
            float4 v = *(const float4*)(p.hB + (size_t)c * HH + tt * 4);
            acc.x += wgt * v.x; acc.y += wgt * v.y; acc.z += wgt * v.z; acc.w += wgt * v.w;
        }
        float di = p.dis[row];
        acc.x *= di; acc.y *= di; acc.z *= di; acc.w *= di;
        *(float4*)(p.hAgg + (size_t)row * HH + tt * 4) = acc;
    }
    gsync(p.bar);

    // ---- P8: colstats (blocks 0-255): colsum + sum x^2 ----
    if (b < 256) {
        float s0 = 0.f, s1 = 0.f, sq = 0.f;
        for (int r = b; r < NN; r += 256) {
            const float* row = p.hAgg + (size_t)r * HH;
            float a = row[t], c = row[t + 256];
            s0 += a; s1 += c;
            sq += a * a + c * c;
        }
        atomicAdd(&p.colsum[t], s0);
        atomicAdd(&p.colsum[t + 256], s1);
#pragma unroll
        for (int o = 32; o > 0; o >>= 1) sq += __shfl_down(sq, o);
        float* red = (float*)SMEM;
        int wv = t >> 6, lane = t & 63;
        __syncthreads();
        if (lane == 0) red[wv] = sq;
        __syncthreads();
        if (t == 0) atomicAdd(p.stats, red[0] + red[1] + red[2] + red[3]);
    }
    gsync(p.bar);

    // ---- P9: pairnorm apply + relu -> hBh/hBl ----
    {
        const float inv = 1.0f / (float)NN;
        float c0 = p.colsum[t], c1 = p.colsum[t + 256];
        float sq = c0 * c0 + c1 * c1;
#pragma unroll
        for (int o = 32; o > 0; o >>= 1) sq += __shfl_down(sq, o);
        float* red = (float*)SMEM;
        float* sbc = red + 4;
        int wv = t >> 6, lane = t & 63;
        __syncthreads();
        if (lane == 0) red[wv] = sq;
        __syncthreads();
        if (t == 0) {
            float msum = red[0] + red[1] + red[2] + red[3];
            *sbc = 1.0f / sqrtf(1e-6f + (p.stats[0] - msum * inv) * inv);
        }
        __syncthreads();
        float s = *sbc;
        for (int i = b * 256 + t; i < NN * HH / 4; i += NBLK * 256) {
            float4 v = ((const float4*)p.hAgg)[i];
            float4 m = ((const float4*)p.colsum)[i & 127];
            float vv[4];
            vv[0] = fmaxf((v.x - m.x * inv) * s, 0.f);
            vv[1] = fmaxf((v.y - m.y * inv) * s, 0.f);
            vv[2] = fmaxf((v.z - m.z * inv) * s, 0.f);
            vv[3] = fmaxf((v.w - m.w * inv) * s, 0.f);
            ushort4 hi, lo;
            unsigned short* hp = (unsigned short*)&hi;
            unsigned short* lp = (unsigned short*)&lo;
#pragma unroll
            for (int j = 0; j < 4; ++j) {
                hp[j] = f2bf(vv[j]);
                lp[j] = f2bf(vv[j] - bf2f(hp[j]));
            }
            *(ushort4*)&p.hBh[(size_t)i * 4] = hi;
            *(ushort4*)&p.hBl[(size_t)i * 4] = lo;
        }
    }
    gsync(p.bar);

    // ---- P10: gemm3 (256 tiles on blocks 0-255) ----
    if (b < 256)
        gemm_tile<32, 64, 0>(p.hBh, p.hBl, p.W2h, p.W2l, p.h3, nullptr, nullptr,
                             CC, b * 32, 0, SMEM);
    gsync(p.bar);

    // ---- P11: spmm64  out = adj_n @ h3 ----
    for (int base = b * 4; base < NN; base += 4 * NBLK) {
        int row = base + (t >> 6);
        int tt = t & 63;
        int cnt = p.nnz[row];
        const int* cp = p.colsI + (size_t)row * MAXNBR;
        float acc = 0.f;
        for (int j = 0; j < cnt; ++j) {
            int c = cp[j];
            acc += p.dis[c] * p.h3[(size_t)c * CC + tt];
        }
        p.out[(size_t)row * CC + tt] = p.dis[row] * acc;
    }
}

// ---------------- launch ----------------

extern "C" void kernel_launch(void* const* d_in, const int* in_sizes, int n_in,
                              void* d_out, int out_size, void* d_ws, size_t ws_size,
                              hipStream_t stream) {
    char* w = (char*)d_ws;
    size_t off = 0;
    auto alloc = [&](size_t bsz) { size_t r = off; off = (off + bsz + 255) & ~(size_t)255; return r; };

    Prm p;
    p.x   = (const float*)d_in[0];
    p.adj = (const float*)d_in[1];
    p.W0  = (const float*)d_in[2];
    p.W1  = (const float*)d_in[3];
    p.W2  = (const float*)d_in[4];
    p.S0  = (const float*)d_in[5];
    p.S1  = (const float*)d_in[6];
    p.S2  = (const float*)d_in[7];
    p.out = (float*)d_out;

    p.bar    = (unsigned*)(w + alloc(256));            // barrier cnt/gen (own line)
    p.degq   = (unsigned*)(w + alloc(512));            // deg queues A (+0) and B (+256B)
    p.hists  = (unsigned*)(w + alloc(4 * 256 * 4));
    p.colsum = (float*)(w + alloc(HH * 4));
    p.stats  = (float*)(w + alloc(256));
    size_t zero_end = off;
    p.nnz    = (int*)(w + alloc(NN * 4));
    p.colsI  = (int*)(w + alloc((size_t)NN * MAXNBR * 4));
    p.dis    = (float*)(w + alloc(NN * 4));
    p.xh  = (unsigned short*)(w + alloc((size_t)NN * FF * 2));
    p.xl  = (unsigned short*)(w + alloc((size_t)NN * FF * 2));
    p.W0h = (unsigned short*)(w + alloc((size_t)HH * FF * 2));
    p.W0l = (unsigned short*)(w + alloc((size_t)HH * FF * 2));
    p.W1h = (unsigned short*)(w + alloc((size_t)HH * HH * 2));
    p.W1l = (unsigned short*)(w + alloc((size_t)HH * HH * 2));
    p.W2h = (unsigned short*)(w + alloc((size_t)CC * HH * 2));
    p.W2l = (unsigned short*)(w + alloc((size_t)CC * HH * 2));
    p.hAh = (unsigned short*)(w + alloc((size_t)NN * HH * 2));
    p.hAl = (unsigned short*)(w + alloc((size_t)NN * HH * 2));
    p.hB  = (float*)(w + alloc((size_t)NN * HH * 4));
    p.hAgg= (float*)(w + alloc((size_t)NN * HH * 4));
    p.hBh = (unsigned short*)(w + alloc((size_t)NN * HH * 2));
    p.hBl = (unsigned short*)(w + alloc((size_t)NN * HH * 2));
    p.h3  = (float*)(w + alloc((size_t)NN * CC * 4));
    (void)ws_size; (void)in_sizes; (void)n_in; (void)out_size;

    hipMemsetAsync(d_ws, 0, zero_end, stream);   // zero barrier/queues/hists/colsum/stats
    mega<<<NBLK, 256, 0, stream>>>(p);
}

// Round 12
// 226.870 us; speedup vs baseline: 6.4834x; 4.2454x over previous
//
#include <hip/hip_runtime.h>
#include <hip/hip_bf16.h>

#define NN 8192
#define FF 512
#define HH 512
#define CC 64
#define NS_TOTAL 557056     // 512*512 + 512*512 + 64*512
#define KSEL 278529u        // 1 + round(0.5 * (557056-1))
#define MAXNBR 96
#define MASKB 2176          // NS_TOTAL / 256

typedef short short8 __attribute__((ext_vector_type(8)));
typedef __bf16 bf16x8 __attribute__((ext_vector_type(8)));
typedef float f32x4 __attribute__((ext_vector_type(4)));

__device__ inline unsigned short f2bf(float f) {   // RNE f32 -> bf16 bits
    unsigned u = __float_as_uint(f);
    u += 0x7fffu + ((u >> 16) & 1u);
    return (unsigned short)(u >> 16);
}
__device__ inline float bf2f(unsigned short h) {
    return __uint_as_float(((unsigned)h) << 16);
}

__device__ inline f32x4 mfma16x16x32(short8 a, short8 b, f32x4 c) {
    return __builtin_amdgcn_mfma_f32_16x16x32_bf16(
        __builtin_bit_cast(bf16x8, a), __builtin_bit_cast(bf16x8, b), c, 0, 0, 0);
}

// async global->LDS, 16B per lane; LDS dest = wave-uniform base + lane*16
__device__ inline void gload_lds16(const unsigned short* g, unsigned short* l) {
    __builtin_amdgcn_global_load_lds(
        (const __attribute__((address_space(1))) void*)g,
        (__attribute__((address_space(3))) void*)l,
        16, 0, 0);
}

// ---- deg: one adjacency row processed by one 256-thread block ----
__device__ void deg_row_body(const float* __restrict__ adj, int* __restrict__ nnz,
                             int* __restrict__ colsI, float* __restrict__ dis,
                             int row, int* dcnt) {
    const int t = threadIdx.x;
    if (t == 0) *dcnt = 0;
    __syncthreads();
    const float4* arow = (const float4*)(adj + (size_t)row * NN);
    int* cp = colsI + (size_t)row * MAXNBR;
    for (int c4 = t; c4 < NN / 4; c4 += 256) {
        float4 v = arow[c4];
        int base = c4 * 4;
        float vv[4] = {v.x, v.y, v.z, v.w};
#pragma unroll
        for (int kq = 0; kq < 4; ++kq) {
            int col = base + kq;
            if (vv[kq] != 0.f || col == row) {
                int s = atomicAdd(dcnt, 1);
                if (s < MAXNBR) cp[s] = col;
            }
        }
    }
    __syncthreads();
    if (t == 0) {
        int c = *dcnt;
        nnz[row] = (c < MAXNBR) ? c : MAXNBR;
        dis[row] = rsqrtf((float)c);
    }
}

// ---- in-block select: find bin b s.t. sum(hist[0..b-1]) < k <= sum(hist[0..b]) ----
__device__ void isel(const unsigned* __restrict__ hist, unsigned k,
                     unsigned& bin, unsigned& krem) {
    __shared__ unsigned sh[256];
    __shared__ unsigned res[2];
    const int t = threadIdx.x;
    __syncthreads();                  // protect sh/res from previous call
    sh[t] = hist[t];
    __syncthreads();
    unsigned pre = 0;
    for (int i = 0; i < t; ++i) pre += sh[i];
    if (pre < k && k <= pre + sh[t]) { res[0] = (unsigned)t; res[1] = k - pre; }
    __syncthreads();
    bin = res[0]; krem = res[1];
}

__device__ void isel_chain(const unsigned* __restrict__ hists, int npass,
                           unsigned& prefix, unsigned& k) {
    prefix = 0; k = KSEL;
    for (int p = 0; p < npass; ++p) {
        unsigned bin, krem;
        isel(hists + p * 256, k, bin, krem);
        prefix |= bin << (24 - 8 * p);
        k = krem;
    }
}

// ---------------- threshold histogram pass (blocks 0-255) + trailing deg blocks ----------------

__global__ __launch_bounds__(256) void hist8_kernel(const float* __restrict__ S0,
                                                    const float* __restrict__ S1,
                                                    const float* __restrict__ S2,
                                                    unsigned* __restrict__ hists, int pass,
                                                    const float* __restrict__ adj,
                                                    int* __restrict__ nnz, int* __restrict__ colsI,
                                                    float* __restrict__ dis, int degRow0) {
    __shared__ unsigned lh[256];
    __shared__ int dcnt;
    if ((int)blockIdx.x >= 256) {
        deg_row_body(adj, nnz, colsI, dis, degRow0 + (int)blockIdx.x - 256, &dcnt);
        return;
    }
    unsigned prefix = 0, k;
    if (pass > 0) isel_chain(hists, pass, prefix, k);
    unsigned pmask = (pass > 0) ? (0xFFFFFFFFu << (32 - 8 * pass)) : 0u;
    int shift = 24 - 8 * pass;
    __syncthreads();
    lh[threadIdx.x] = 0;
    __syncthreads();
    for (int idx = blockIdx.x * 256 + threadIdx.x; idx < NS_TOTAL; idx += 65536) {
        float v = (idx < 262144) ? S0[idx] : (idx < 524288) ? S1[idx - 262144] : S2[idx - 524288];
        unsigned key = __float_as_uint(fabsf(v));
        if ((key & pmask) == prefix)
            atomicAdd(&lh[(key >> shift) & 0xffu], 1u);
    }
    __syncthreads();
    unsigned c = lh[threadIdx.x];
    if (c) atomicAdd(&hists[pass * 256 + threadIdx.x], c);
}

// ---------------- fused: masked weights -> hi/lo bf16  AND  x -> hi/lo bf16 ----------------

__global__ __launch_bounds__(256) void mask_split_fused(
        const float* __restrict__ W0, const float* __restrict__ W1,
        const float* __restrict__ W2, const float* __restrict__ S0,
        const float* __restrict__ S1, const float* __restrict__ S2,
        const unsigned* __restrict__ hists,
        unsigned short* __restrict__ W0h, unsigned short* __restrict__ W0l,
        unsigned short* __restrict__ W1h, unsigned short* __restrict__ W1l,
        unsigned short* __restrict__ W2h, unsigned short* __restrict__ W2l,
        const float* __restrict__ X,
        unsigned short* __restrict__ Xh, unsigned short* __restrict__ Xl) {
    if (blockIdx.x >= MASKB) {
        // ---- x split branch ----
        int i = (blockIdx.x - MASKB) * 256 + threadIdx.x;   // one float4; 4096 blocks
        float4 v = ((const float4*)X)[i];
        float vv[4] = {v.x, v.y, v.z, v.w};
        ushort4 hi, lo;
        unsigned short* hp = (unsigned short*)&hi;
        unsigned short* lp = (unsigned short*)&lo;
#pragma unroll
        for (int j = 0; j < 4; ++j) {
            hp[j] = f2bf(vv[j]);
            lp[j] = f2bf(vv[j] - bf2f(hp[j]));
        }
        *(ushort4*)&Xh[(size_t)i * 4] = hi;
        *(ushort4*)&Xl[(size_t)i * 4] = lo;
        return;
    }
    // ---- mask branch ----
    unsigned prefix, k;
    isel_chain(hists, 4, prefix, k);
    float thr = __uint_as_float(prefix);
    int idx = blockIdx.x * 256 + threadIdx.x;           // < NS_TOTAL exactly
    const float* W; const float* S; unsigned short* Yh; unsigned short* Yl; int i;
    if (idx < 262144)      { W = W0; S = S0; Yh = W0h; Yl = W0l; i = idx; }
    else if (idx < 524288) { W = W1; S = S1; Yh = W1h; Yl = W1l; i = idx - 262144; }
    else                   { W = W2; S = S2; Yh = W2h; Yl = W2l; i = idx - 524288; }
    float v = (fabsf(S[i]) > thr) ? W[i] : 0.f;
    unsigned short hi = f2bf(v);
    Yh[i] = hi;
    Yl[i] = f2bf(v - bf2f(hi));
}

// ---------------- hi/lo 3-term MFMA GEMM, bank-swizzled (+ trailing deg blocks) ----------
// C = Ah*Bh^T + Ah*Bl^T + Al*Bh^T over K=512. BK=32, 4 waves (2x2), single LDS buffer.

template<int BMt, int BNt, int WRITE_SPLIT>
__global__ __launch_bounds__(256) void gemm_hl(
        const unsigned short* __restrict__ Ah, const unsigned short* __restrict__ Al,
        const unsigned short* __restrict__ Bh, const unsigned short* __restrict__ Bl,
        float* __restrict__ Cf, unsigned short* __restrict__ Ch,
        unsigned short* __restrict__ Cl, int Nn, int gridN, int gemmBlocks,
        const float* __restrict__ adj, int* __restrict__ nnz, int* __restrict__ colsI,
        float* __restrict__ dis, int degRow0) {
    constexpr int BK = 32;
    constexpr int MF = BMt / 32, NF = BNt / 32;
    __shared__ __align__(16) unsigned short AhS[BMt * BK], AlS[BMt * BK];
    __shared__ __align__(16) unsigned short BhS[BNt * BK], BlS[BNt * BK];
    __shared__ int dcnt;

    if ((int)blockIdx.x >= gemmBlocks) {
        deg_row_body(adj, nnz, colsI, dis, degRow0 + (int)blockIdx.x - gemmBlocks, &dcnt);
        return;
    }
    // ---- gemm branch ----
    const int tid = threadIdx.x, lane = tid & 63, wid = tid >> 6;
    const int wr = wid >> 1, wc = wid & 1;
    const int bm = ((int)blockIdx.x / gridN) * BMt;
    const int bn = ((int)blockIdx.x % gridN) * BNt;
    const int r16 = lane & 15, kg = lane >> 4;
    const int srow = lane >> 2;
    const int scol = ((lane & 3) ^ ((srow >> 1) & 3)) * 8;   // pre-swizzled source slot
    constexpr int cA = BMt / 16, cB = BNt / 16, CPW = (2 * cA + 2 * cB) / 4;
    f32x4 acc[MF][NF] = {};

    const int ksw = (kg ^ ((r16 >> 1) & 3)) * 8;             // read-side swizzle
    const unsigned short* pAh = &AhS[(wr * (BMt / 2) + r16) * BK + ksw];
    const unsigned short* pAl = &AlS[(wr * (BMt / 2) + r16) * BK + ksw];
    const unsigned short* pBh = &BhS[(wc * (BNt / 2) + r16) * BK + ksw];
    const unsigned short* pBl = &BlS[(wc * (BNt / 2) + r16) * BK + ksw];

    for (int k0 = 0; k0 < 512; k0 += BK) {
        __syncthreads();   // previous compute done reading LDS
#pragma unroll
        for (int i = 0; i < CPW; ++i) {
            int c = wid * CPW + i;
            const unsigned short* src; unsigned short* dst; int cc, r0;
            if (c < cA)               { src = Ah; dst = AhS; cc = c;               r0 = bm + cc * 16; }
            else if (c < 2 * cA)      { src = Al; dst = AlS; cc = c - cA;          r0 = bm + cc * 16; }
            else if (c < 2 * cA + cB) { src = Bh; dst = BhS; cc = c - 2 * cA;      r0 = bn + cc * 16; }
            else                      { src = Bl; dst = BlS; cc = c - 2 * cA - cB; r0 = bn + cc * 16; }
            gload_lds16(src + (size_t)(r0 + srow) * 512 + k0 + scol, dst + cc * 512);
        }
        __syncthreads();   // tiles resident
        short8 bhf[NF], blf[NF];
#pragma unroll
        for (int n = 0; n < NF; ++n) {
            bhf[n] = *(const short8*)(pBh + n * 16 * BK);
            blf[n] = *(const short8*)(pBl + n * 16 * BK);
        }
#pragma unroll
        for (int m = 0; m < MF; ++m) {
            short8 ahf = *(const short8*)(pAh + m * 16 * BK);
            short8 alf = *(const short8*)(pAl + m * 16 * BK);
#pragma unroll
            for (int n = 0; n < NF; ++n) {
                acc[m][n] = mfma16x16x32(ahf, bhf[n], acc[m][n]);
                acc[m][n] = mfma16x16x32(ahf, blf[n], acc[m][n]);
                acc[m][n] = mfma16x16x32(alf, bhf[n], acc[m][n]);
            }
        }
    }
    // epilogue: C/D layout col = lane&15, row = (lane>>4)*4 + j  [m89-verified]
#pragma unroll
    for (int m = 0; m < MF; ++m) {
#pragma unroll
        for (int n = 0; n < NF; ++n) {
            int row0 = bm + wr * (BMt / 2) + m * 16 + kg * 4;
            int col  = bn + wc * (BNt / 2) + n * 16 + r16;
#pragma unroll
            for (int j = 0; j < 4; ++j) {
                float v = acc[m][n][j];
                if (WRITE_SPLIT) {
                    unsigned short hi = f2bf(v);
                    size_t base = (size_t)(row0 + j) * Nn + col;
                    Ch[base] = hi;
                    Cl[base] = f2bf(v - bf2f(hi));
                } else {
                    Cf[(size_t)(row0 + j) * Nn + col] = v;
                }
            }
        }
    }
}

// ---------------- SpMM: Hout[row,:] = dis[row] * sum_nbr dis[c] * Hin[c,:] ----------------

__global__ void spmm512(const int* __restrict__ nnz, const int* __restrict__ colsI,
                        const float* __restrict__ dis, const float* __restrict__ Hin,
                        float* __restrict__ Hout) {
    int row = blockIdx.x;
    int t = threadIdx.x;  // 128
    int cnt = nnz[row];
    const int* cp = colsI + (size_t)row * MAXNBR;
    float4 acc = make_float4(0.f, 0.f, 0.f, 0.f);
    for (int j = 0; j < cnt; ++j) {
        int c = cp[j];
        float wgt = dis[c];
        float4 v = *(const float4*)(Hin + (size_t)c * HH + t * 4);
        acc.x += wgt * v.x; acc.y += wgt * v.y; acc.z += wgt * v.z; acc.w += wgt * v.w;
    }
    float di = dis[row];
    acc.x *= di; acc.y *= di; acc.z *= di; acc.w *= di;
    *(float4*)(Hout + (size_t)row * HH + t * 4) = acc;
}

__global__ void spmm64(const int* __restrict__ nnz, const int* __restrict__ colsI,
                       const float* __restrict__ dis, const float* __restrict__ Hin,
                       float* __restrict__ Hout) {
    int row = blockIdx.x;
    int t = threadIdx.x;  // 64
    int cnt = nnz[row];
    const int* cp = colsI + (size_t)row * MAXNBR;
    float acc = 0.f;
    for (int j = 0; j < cnt; ++j) {
        int c = cp[j];
        acc += dis[c] * Hin[(size_t)c * CC + t];
    }
    Hout[(size_t)row * CC + t] = dis[row] * acc;
}

// ---------------- PairNorm (fused stats): colsum + total sum-of-squares in one pass ----------

__global__ void colstats_kernel(const float* __restrict__ X, float* __restrict__ colsum,
                                float* __restrict__ stats) {
    int t = threadIdx.x;  // 256 threads, 256 blocks
    float s0 = 0.f, s1 = 0.f, sq = 0.f;
    for (int r = blockIdx.x; r < NN; r += 256) {
        const float* row = X + (size_t)r * HH;
        float a = row[t], b = row[t + 256];
        s0 += a; s1 += b;
        sq += a * a + b * b;
    }
    atomicAdd(&colsum[t], s0);
    atomicAdd(&colsum[t + 256], s1);
#pragma unroll
    for (int o = 32; o > 0; o >>= 1) sq += __shfl_down(sq, o);
    __shared__ float red[4];
    int wv = t >> 6, lane = t & 63;
    if (lane == 0) red[wv] = sq;
    __syncthreads();
    if (t == 0) atomicAdd(stats, red[0] + red[1] + red[2] + red[3]);
}

// pairnorm normalize + relu -> hi/lo bf16 arrays
__global__ __launch_bounds__(256) void pn_apply_split(const float* __restrict__ X,
                                                      const float* __restrict__ colsum,
                                                      const float* __restrict__ stats,
                                                      unsigned short* __restrict__ Yh,
                                                      unsigned short* __restrict__ Yl) {
    const float inv = 1.0f / (float)NN;
    int t = threadIdx.x;
    // block-local: msum = sum_c colsum[c]^2 ;  sum|x-m|^2 = stats - msum/N
    float c0 = colsum[t], c1 = colsum[t + 256];
    float sq = c0 * c0 + c1 * c1;
#pragma unroll
    for (int o = 32; o > 0; o >>= 1) sq += __shfl_down(sq, o);
    __shared__ float red[4];
    __shared__ float sbc;
    int wv = t >> 6, lane = t & 63;
    if (lane == 0) red[wv] = sq;
    __syncthreads();
    if (t == 0) {
        float msum = red[0] + red[1] + red[2] + red[3];
        sbc = 1.0f / sqrtf(1e-6f + (stats[0] - msum * inv) * inv);
    }
    __syncthreads();
    float s = sbc;

    int i = blockIdx.x * 256 + t;   // one float4; NN*HH/4 total
    float4 v = ((const float4*)X)[i];
    float4 m = ((const float4*)colsum)[i & 127];
    float vv[4];
    vv[0] = fmaxf((v.x - m.x * inv) * s, 0.f);
    vv[1] = fmaxf((v.y - m.y * inv) * s, 0.f);
    vv[2] = fmaxf((v.z - m.z * inv) * s, 0.f);
    vv[3] = fmaxf((v.w - m.w * inv) * s, 0.f);
    ushort4 hi, lo;
    unsigned short* hp = (unsigned short*)&hi;
    unsigned short* lp = (unsigned short*)&lo;
#pragma unroll
    for (int j = 0; j < 4; ++j) {
        hp[j] = f2bf(vv[j]);
        lp[j] = f2bf(vv[j] - bf2f(hp[j]));
    }
    *(ushort4*)&Yh[(size_t)i * 4] = hi;
    *(ushort4*)&Yl[(size_t)i * 4] = lo;
}

// ---------------- launch ----------------

extern "C" void kernel_launch(void* const* d_in, const int* in_sizes, int n_in,
                              void* d_out, int out_size, void* d_ws, size_t ws_size,
                              hipStream_t stream) {
    const float* x   = (const float*)d_in[0];
    const float* adj = (const float*)d_in[1];
    const float* W0  = (const float*)d_in[2];
    const float* W1  = (const float*)d_in[3];
    const float* W2  = (const float*)d_in[4];
    const float* S0  = (const float*)d_in[5];
    const float* S1  = (const float*)d_in[6];
    const float* S2  = (const float*)d_in[7];
    float* out = (float*)d_out;

    char* w = (char*)d_ws;
    size_t off = 0;
    auto alloc = [&](size_t b) { size_t r = off; off = (off + b + 255) & ~(size_t)255; return r; };
    unsigned* hists = (unsigned*)(w + alloc(4 * 256 * 4));   // hists[pass][256]
    float* colsum   = (float*)(w + alloc(HH * 4));
    float* stats    = (float*)(w + alloc(256));
    size_t zero_end = off;
    int* nnz   = (int*)(w + alloc(NN * 4));
    int* colsI = (int*)(w + alloc((size_t)NN * MAXNBR * 4));
    float* dis = (float*)(w + alloc(NN * 4));
    unsigned short* xh  = (unsigned short*)(w + alloc((size_t)NN * FF * 2));
    unsigned short* xl  = (unsigned short*)(w + alloc((size_t)NN * FF * 2));
    unsigned short* W0h = (unsigned short*)(w + alloc((size_t)HH * FF * 2));
    unsigned short* W0l = (unsigned short*)(w + alloc((size_t)HH * FF * 2));
    unsigned short* W1h = (unsigned short*)(w + alloc((size_t)HH * HH * 2));
    unsigned short* W1l = (unsigned short*)(w + alloc((size_t)HH * HH * 2));
    unsigned short* W2h = (unsigned short*)(w + alloc((size_t)CC * HH * 2));
    unsigned short* W2l = (unsigned short*)(w + alloc((size_t)CC * HH * 2));
    unsigned short* hAh = (unsigned short*)(w + alloc((size_t)NN * HH * 2));
    unsigned short* hAl = (unsigned short*)(w + alloc((size_t)NN * HH * 2));
    float* hB   = (float*)(w + alloc((size_t)NN * HH * 4));
    float* hAgg = (float*)(w + alloc((size_t)NN * HH * 4));
    unsigned short* hBh = (unsigned short*)(w + alloc((size_t)NN * HH * 2));
    unsigned short* hBl = (unsigned short*)(w + alloc((size_t)NN * HH * 2));
    float* h3   = (float*)(w + alloc((size_t)NN * CC * 4));
    (void)ws_size; (void)in_sizes; (void)n_in; (void)out_size;

    hipMemsetAsync(d_ws, 0, zero_end, stream);

    // threshold: 4 x 8-bit histogram passes (selects re-derived in-block)
    // + 1024 trailing deg blocks each (rows 0..4095 hide under the otherwise-idle select chain)
    for (int p = 0; p < 4; ++p)
        hist8_kernel<<<256 + 1024, 256, 0, stream>>>(S0, S1, S2, hists, p,
                                                     adj, nnz, colsI, dis, p * 1024);

    // fused: masked weights -> hi/lo bf16  AND  x -> hi/lo bf16
    mask_split_fused<<<MASKB + NN * FF / 4 / 256, 256, 0, stream>>>(
        W0, W1, W2, S0, S1, S2, hists, W0h, W0l, W1h, W1l, W2h, W2l, x, xh, xl);

    // gemm1 (+ deg rows 4096..6143); gemm2 (+ deg rows 6144..8191)
    const int g12 = (NN / 64) * (HH / 128);   // 512 gemm blocks
    gemm_hl<64, 128, 1><<<g12 + 2048, 256, 0, stream>>>(
        xh, xl, W0h, W0l, nullptr, hAh, hAl, HH, HH / 128, g12,
        adj, nnz, colsI, dis, 4096);
    gemm_hl<64, 128, 0><<<g12 + 2048, 256, 0, stream>>>(
        hAh, hAl, W1h, W1l, hB, nullptr, nullptr, HH, HH / 128, g12,
        adj, nnz, colsI, dis, 6144);

    // aggregation
    spmm512<<<NN, 128, 0, stream>>>(nnz, colsI, dis, hB, hAgg);

    // pairnorm stats (single fused pass) + apply+relu -> hi/lo bf16
    colstats_kernel<<<256, 256, 0, stream>>>(hAgg, colsum, stats);
    pn_apply_split<<<(NN * HH / 4) / 256, 256, 0, stream>>>(hAgg, colsum, stats, hBh, hBl);

    // h3 = hB @ Wm2^T ; out = adj_n @ h3
    const int g3 = (NN / 32) * (CC / 64);     // 256 blocks
    gemm_hl<32, 64, 0><<<g3, 256, 0, stream>>>(
        hBh, hBl, W2h, W2l, h3, nullptr, nullptr, CC, CC / 64, g3,
        nullptr, nullptr, nullptr, nullptr, 0);
    spmm64<<<NN, 64, 0, stream>>>(nnz, colsI, dis, h3, out);
}

// Round 13
// 226.062 us; speedup vs baseline: 6.5066x; 1.0036x over previous
//
#include <hip/hip_runtime.h>
#include <hip/hip_bf16.h>

#define NN 8192
#define FF 512
#define HH 512
#define CC 64
#define NS_TOTAL 557056     // 512*512 + 512*512 + 64*512
#define KSEL 278529u        // 1 + round(0.5 * (557056-1))
#define MAXNBR 96
#define MASKB 2176          // NS_TOTAL / 256

typedef short short8 __attribute__((ext_vector_type(8)));
typedef __bf16 bf16x8 __attribute__((ext_vector_type(8)));
typedef float f32x4 __attribute__((ext_vector_type(4)));

__device__ inline unsigned short f2bf(float f) {   // RNE f32 -> bf16 bits
    unsigned u = __float_as_uint(f);
    u += 0x7fffu + ((u >> 16) & 1u);
    return (unsigned short)(u >> 16);
}
__device__ inline float bf2f(unsigned short h) {
    return __uint_as_float(((unsigned)h) << 16);
}

__device__ inline f32x4 mfma16x16x32(short8 a, short8 b, f32x4 c) {
    return __builtin_amdgcn_mfma_f32_16x16x32_bf16(
        __builtin_bit_cast(bf16x8, a), __builtin_bit_cast(bf16x8, b), c, 0, 0, 0);
}

// async global->LDS, 16B per lane; LDS dest = wave-uniform base + lane*16
__device__ inline void gload_lds16(const unsigned short* g, unsigned short* l) {
    __builtin_amdgcn_global_load_lds(
        (const __attribute__((address_space(1))) void*)g,
        (__attribute__((address_space(3))) void*)l,
        16, 0, 0);
}

// ---- deg: one adjacency row processed by one 256-thread block ----
__device__ void deg_row_body(const float* __restrict__ adj, int* __restrict__ nnz,
                             int* __restrict__ colsI, float* __restrict__ dis,
                             int row, int* dcnt) {
    const int t = threadIdx.x;
    if (t == 0) *dcnt = 0;
    __syncthreads();
    const float4* arow = (const float4*)(adj + (size_t)row * NN);
    int* cp = colsI + (size_t)row * MAXNBR;
    for (int c4 = t; c4 < NN / 4; c4 += 256) {
        float4 v = arow[c4];
        int base = c4 * 4;
        float vv[4] = {v.x, v.y, v.z, v.w};
#pragma unroll
        for (int kq = 0; kq < 4; ++kq) {
            int col = base + kq;
            if (vv[kq] != 0.f || col == row) {
                int s = atomicAdd(dcnt, 1);
                if (s < MAXNBR) cp[s] = col;
            }
        }
    }
    __syncthreads();
    if (t == 0) {
        int c = *dcnt;
        nnz[row] = (c < MAXNBR) ? c : MAXNBR;
        dis[row] = rsqrtf((float)c);
    }
}

// ---- in-block select: find bin b s.t. sum(hist[0..b-1]) < k <= sum(hist[0..b]) ----
__device__ void isel(const unsigned* __restrict__ hist, unsigned k,
                     unsigned& bin, unsigned& krem) {
    __shared__ unsigned sh[256];
    __shared__ unsigned res[2];
    const int t = threadIdx.x;
    __syncthreads();                  // protect sh/res from previous call
    sh[t] = hist[t];
    __syncthreads();
    unsigned pre = 0;
    for (int i = 0; i < t; ++i) pre += sh[i];
    if (pre < k && k <= pre + sh[t]) { res[0] = (unsigned)t; res[1] = k - pre; }
    __syncthreads();
    bin = res[0]; krem = res[1];
}

__device__ void isel_chain(const unsigned* __restrict__ hists, int npass,
                           unsigned& prefix, unsigned& k) {
    prefix = 0; k = KSEL;
    for (int p = 0; p < npass; ++p) {
        unsigned bin, krem;
        isel(hists + p * 256, k, bin, krem);
        prefix |= bin << (24 - 8 * p);
        k = krem;
    }
}

// ---------------- threshold histogram pass (blocks 0-255) + 2048 trailing deg blocks ---------

__global__ __launch_bounds__(256) void hist8_kernel(const float* __restrict__ S0,
                                                    const float* __restrict__ S1,
                                                    const float* __restrict__ S2,
                                                    unsigned* __restrict__ hists, int pass,
                                                    const float* __restrict__ adj,
                                                    int* __restrict__ nnz, int* __restrict__ colsI,
                                                    float* __restrict__ dis, int degRow0) {
    __shared__ unsigned lh[256];
    __shared__ int dcnt;
    if ((int)blockIdx.x >= 256) {
        deg_row_body(adj, nnz, colsI, dis, degRow0 + (int)blockIdx.x - 256, &dcnt);
        return;
    }
    unsigned prefix = 0, k;
    if (pass > 0) isel_chain(hists, pass, prefix, k);
    unsigned pmask = (pass > 0) ? (0xFFFFFFFFu << (32 - 8 * pass)) : 0u;
    int shift = 24 - 8 * pass;
    __syncthreads();
    lh[threadIdx.x] = 0;
    __syncthreads();
    for (int idx = blockIdx.x * 256 + threadIdx.x; idx < NS_TOTAL; idx += 65536) {
        float v = (idx < 262144) ? S0[idx] : (idx < 524288) ? S1[idx - 262144] : S2[idx - 524288];
        unsigned key = __float_as_uint(fabsf(v));
        if ((key & pmask) == prefix)
            atomicAdd(&lh[(key >> shift) & 0xffu], 1u);
    }
    __syncthreads();
    unsigned c = lh[threadIdx.x];
    if (c) atomicAdd(&hists[pass * 256 + threadIdx.x], c);
}

// ---------------- fused: masked weights -> hi/lo bf16  AND  x -> hi/lo bf16 ----------------

__global__ __launch_bounds__(256) void mask_split_fused(
        const float* __restrict__ W0, const float* __restrict__ W1,
        const float* __restrict__ W2, const float* __restrict__ S0,
        const float* __restrict__ S1, const float* __restrict__ S2,
        const unsigned* __restrict__ hists,
        unsigned short* __restrict__ W0h, unsigned short* __restrict__ W0l,
        unsigned short* __restrict__ W1h, unsigned short* __restrict__ W1l,
        unsigned short* __restrict__ W2h, unsigned short* __restrict__ W2l,
        const float* __restrict__ X,
        unsigned short* __restrict__ Xh, unsigned short* __restrict__ Xl) {
    if (blockIdx.x >= MASKB) {
        // ---- x split branch ----
        int i = (blockIdx.x - MASKB) * 256 + threadIdx.x;   // one float4; 4096 blocks
        float4 v = ((const float4*)X)[i];
        float vv[4] = {v.x, v.y, v.z, v.w};
        ushort4 hi, lo;
        unsigned short* hp = (unsigned short*)&hi;
        unsigned short* lp = (unsigned short*)&lo;
#pragma unroll
        for (int j = 0; j < 4; ++j) {
            hp[j] = f2bf(vv[j]);
            lp[j] = f2bf(vv[j] - bf2f(hp[j]));
        }
        *(ushort4*)&Xh[(size_t)i * 4] = hi;
        *(ushort4*)&Xl[(size_t)i * 4] = lo;
        return;
    }
    // ---- mask branch ----
    unsigned prefix, k;
    isel_chain(hists, 4, prefix, k);
    float thr = __uint_as_float(prefix);
    int idx = blockIdx.x * 256 + threadIdx.x;           // < NS_TOTAL exactly
    const float* W; const float* S; unsigned short* Yh; unsigned short* Yl; int i;
    if (idx < 262144)      { W = W0; S = S0; Yh = W0h; Yl = W0l; i = idx; }
    else if (idx < 524288) { W = W1; S = S1; Yh = W1h; Yl = W1l; i = idx - 262144; }
    else                   { W = W2; S = S2; Yh = W2h; Yl = W2l; i = idx - 524288; }
    float v = (fabsf(S[i]) > thr) ? W[i] : 0.f;
    unsigned short hi = f2bf(v);
    Yh[i] = hi;
    Yl[i] = f2bf(v - bf2f(hi));
}

// ---------------- hi/lo 3-term MFMA GEMM, PURE, canonical 2-phase double-buffer ----------
// C = Ah*Bh^T + Ah*Bl^T + Al*Bh^T over K=512. BK=32, 4 waves (2x2).
// STAGE(next) issued BEFORE COMPUTE(cur); ONE barrier per K-step (its vmcnt(0) drain
// lands the in-flight loads that had the whole MFMA phase to complete). 48KB LDS,
// 3 blocks/CU; grid=512 -> 2 blocks/CU resident, so in-block pipelining is the overlap.

template<int BMt, int BNt, int WRITE_SPLIT>
__global__ __launch_bounds__(256) void gemm_hl(
        const unsigned short* __restrict__ Ah, const unsigned short* __restrict__ Al,
        const unsigned short* __restrict__ Bh, const unsigned short* __restrict__ Bl,
        float* __restrict__ Cf, unsigned short* __restrict__ Ch,
        unsigned short* __restrict__ Cl, int Nn, int gridN) {
    constexpr int BK = 32;
    constexpr int MF = BMt / 32, NF = BNt / 32;
    __shared__ __align__(16) unsigned short AhS[2][BMt * BK], AlS[2][BMt * BK];
    __shared__ __align__(16) unsigned short BhS[2][BNt * BK], BlS[2][BNt * BK];

    const int tid = threadIdx.x, lane = tid & 63, wid = tid >> 6;
    const int wr = wid >> 1, wc = wid & 1;
    const int bm = ((int)blockIdx.x / gridN) * BMt;
    const int bn = ((int)blockIdx.x % gridN) * BNt;
    const int r16 = lane & 15, kg = lane >> 4;
    const int srow = lane >> 2;
    const int scol = ((lane & 3) ^ ((srow >> 1) & 3)) * 8;   // pre-swizzled source slot
    constexpr int cA = BMt / 16, cB = BNt / 16, CPW = (2 * cA + 2 * cB) / 4;
    f32x4 acc[MF][NF] = {};
    const int ksw = (kg ^ ((r16 >> 1) & 3)) * 8;             // read-side swizzle

    auto STAGE = [&](int bf, int k0) {
#pragma unroll
        for (int i = 0; i < CPW; ++i) {
            int c = wid * CPW + i;
            const unsigned short* src; unsigned short* dst; int cc, r0;
            if (c < cA)               { src = Ah; dst = AhS[bf]; cc = c;               r0 = bm + cc * 16; }
            else if (c < 2 * cA)      { src = Al; dst = AlS[bf]; cc = c - cA;          r0 = bm + cc * 16; }
            else if (c < 2 * cA + cB) { src = Bh; dst = BhS[bf]; cc = c - 2 * cA;      r0 = bn + cc * 16; }
            else                      { src = Bl; dst = BlS[bf]; cc = c - 2 * cA - cB; r0 = bn + cc * 16; }
            gload_lds16(src + (size_t)(r0 + srow) * 512 + k0 + scol, dst + cc * 512);
        }
    };
    auto COMPUTE = [&](int bf) {
        const unsigned short* pAh = &AhS[bf][(wr * (BMt / 2) + r16) * BK + ksw];
        const unsigned short* pAl = &AlS[bf][(wr * (BMt / 2) + r16) * BK + ksw];
        const unsigned short* pBh = &BhS[bf][(wc * (BNt / 2) + r16) * BK + ksw];
        const unsigned short* pBl = &BlS[bf][(wc * (BNt / 2) + r16) * BK + ksw];
        short8 bhf[NF], blf[NF];
#pragma unroll
        for (int n = 0; n < NF; ++n) {
            bhf[n] = *(const short8*)(pBh + n * 16 * BK);
            blf[n] = *(const short8*)(pBl + n * 16 * BK);
        }
#pragma unroll
        for (int m = 0; m < MF; ++m) {
            short8 ahf = *(const short8*)(pAh + m * 16 * BK);
            short8 alf = *(const short8*)(pAl + m * 16 * BK);
#pragma unroll
            for (int n = 0; n < NF; ++n) {
                acc[m][n] = mfma16x16x32(ahf, bhf[n], acc[m][n]);
                acc[m][n] = mfma16x16x32(ahf, blf[n], acc[m][n]);
                acc[m][n] = mfma16x16x32(alf, bhf[n], acc[m][n]);
            }
        }
    };

    STAGE(0, 0);
    __syncthreads();                         // vmcnt(0): buf0 resident
    for (int k0 = 0; k0 < 512; k0 += 64) {   // two half-steps per iter (static buf indices)
        STAGE(1, k0 + 32);                   // next loads fly under COMPUTE(0)
        COMPUTE(0);
        __syncthreads();                     // buf1 resident; buf0 free
        if (k0 + 64 < 512)
            STAGE(0, k0 + 64);
        COMPUTE(1);
        __syncthreads();                     // buf0 resident; buf1 free
    }
    // epilogue: C/D layout col = lane&15, row = (lane>>4)*4 + j  [m89-verified]
#pragma unroll
    for (int m = 0; m < MF; ++m) {
#pragma unroll
        for (int n = 0; n < NF; ++n) {
            int row0 = bm + wr * (BMt / 2) + m * 16 + kg * 4;
            int col  = bn + wc * (BNt / 2) + n * 16 + r16;
#pragma unroll
            for (int j = 0; j < 4; ++j) {
                float v = acc[m][n][j];
                if (WRITE_SPLIT) {
                    unsigned short hi = f2bf(v);
                    size_t base = (size_t)(row0 + j) * Nn + col;
                    Ch[base] = hi;
                    Cl[base] = f2bf(v - bf2f(hi));
                } else {
                    Cf[(size_t)(row0 + j) * Nn + col] = v;
                }
            }
        }
    }
}

// ---------------- SpMM: Hout[row,:] = dis[row] * sum_nbr dis[c] * Hin[c,:] ----------------

__global__ void spmm512(const int* __restrict__ nnz, const int* __restrict__ colsI,
                        const float* __restrict__ dis, const float* __restrict__ Hin,
                        float* __restrict__ Hout) {
    int row = blockIdx.x;
    int t = threadIdx.x;  // 128
    int cnt = nnz[row];
    const int* cp = colsI + (size_t)row * MAXNBR;
    float4 acc = make_float4(0.f, 0.f, 0.f, 0.f);
    for (int j = 0; j < cnt; ++j) {
        int c = cp[j];
        float wgt = dis[c];
        float4 v = *(const float4*)(Hin + (size_t)c * HH + t * 4);
        acc.x += wgt * v.x; acc.y += wgt * v.y; acc.z += wgt * v.z; acc.w += wgt * v.w;
    }
    float di = dis[row];
    acc.x *= di; acc.y *= di; acc.z *= di; acc.w *= di;
    *(float4*)(Hout + (size_t)row * HH + t * 4) = acc;
}

__global__ void spmm64(const int* __restrict__ nnz, const int* __restrict__ colsI,
                       const float* __restrict__ dis, const float* __restrict__ Hin,
                       float* __restrict__ Hout) {
    int row = blockIdx.x;
    int t = threadIdx.x;  // 64
    int cnt = nnz[row];
    const int* cp = colsI + (size_t)row * MAXNBR;
    float acc = 0.f;
    for (int j = 0; j < cnt; ++j) {
        int c = cp[j];
        acc += dis[c] * Hin[(size_t)c * CC + t];
    }
    Hout[(size_t)row * CC + t] = dis[row] * acc;
}

// ---------------- PairNorm (fused stats): colsum + total sum-of-squares in one pass ----------

__global__ void colstats_kernel(const float* __restrict__ X, float* __restrict__ colsum,
                                float* __restrict__ stats) {
    int t = threadIdx.x;  // 256 threads, 256 blocks
    float s0 = 0.f, s1 = 0.f, sq = 0.f;
    for (int r = blockIdx.x; r < NN; r += 256) {
        const float* row = X + (size_t)r * HH;
        float a = row[t], b = row[t + 256];
        s0 += a; s1 += b;
        sq += a * a + b * b;
    }
    atomicAdd(&colsum[t], s0);
    atomicAdd(&colsum[t + 256], s1);
#pragma unroll
    for (int o = 32; o > 0; o >>= 1) sq += __shfl_down(sq, o);
    __shared__ float red[4];
    int wv = t >> 6, lane = t & 63;
    if (lane == 0) red[wv] = sq;
    __syncthreads();
    if (t == 0) atomicAdd(stats, red[0] + red[1] + red[2] + red[3]);
}

// pairnorm normalize + relu -> hi/lo bf16 arrays
__global__ __launch_bounds__(256) void pn_apply_split(const float* __restrict__ X,
                                                      const float* __restrict__ colsum,
                                                      const float* __restrict__ stats,
                                                      unsigned short* __restrict__ Yh,
                                                      unsigned short* __restrict__ Yl) {
    const float inv = 1.0f / (float)NN;
    int t = threadIdx.x;
    // block-local: msum = sum_c colsum[c]^2 ;  sum|x-m|^2 = stats - msum/N
    float c0 = colsum[t], c1 = colsum[t + 256];
    float sq = c0 * c0 + c1 * c1;
#pragma unroll
    for (int o = 32; o > 0; o >>= 1) sq += __shfl_down(sq, o);
    __shared__ float red[4];
    __shared__ float sbc;
    int wv = t >> 6, lane = t & 63;
    if (lane == 0) red[wv] = sq;
    __syncthreads();
    if (t == 0) {
        float msum = red[0] + red[1] + red[2] + red[3];
        sbc = 1.0f / sqrtf(1e-6f + (stats[0] - msum * inv) * inv);
    }
    __syncthreads();
    float s = sbc;

    int i = blockIdx.x * 256 + t;   // one float4; NN*HH/4 total
    float4 v = ((const float4*)X)[i];
    float4 m = ((const float4*)colsum)[i & 127];
    float vv[4];
    vv[0] = fmaxf((v.x - m.x * inv) * s, 0.f);
    vv[1] = fmaxf((v.y - m.y * inv) * s, 0.f);
    vv[2] = fmaxf((v.z - m.z * inv) * s, 0.f);
    vv[3] = fmaxf((v.w - m.w * inv) * s, 0.f);
    ushort4 hi, lo;
    unsigned short* hp = (unsigned short*)&hi;
    unsigned short* lp = (unsigned short*)&lo;
#pragma unroll
    for (int j = 0; j < 4; ++j) {
        hp[j] = f2bf(vv[j]);
        lp[j] = f2bf(vv[j] - bf2f(hp[j]));
    }
    *(ushort4*)&Yh[(size_t)i * 4] = hi;
    *(ushort4*)&Yl[(size_t)i * 4] = lo;
}

// ---------------- launch ----------------

extern "C" void kernel_launch(void* const* d_in, const int* in_sizes, int n_in,
                              void* d_out, int out_size, void* d_ws, size_t ws_size,
                              hipStream_t stream) {
    const float* x   = (const float*)d_in[0];
    const float* adj = (const float*)d_in[1];
    const float* W0  = (const float*)d_in[2];
    const float* W1  = (const float*)d_in[3];
    const float* W2  = (const float*)d_in[4];
    const float* S0  = (const float*)d_in[5];
    const float* S1  = (const float*)d_in[6];
    const float* S2  = (const float*)d_in[7];
    float* out = (float*)d_out;

    char* w = (char*)d_ws;
    size_t off = 0;
    auto alloc = [&](size_t b) { size_t r = off; off = (off + b + 255) & ~(size_t)255; return r; };
    unsigned* hists = (unsigned*)(w + alloc(4 * 256 * 4));   // hists[pass][256]
    float* colsum   = (float*)(w + alloc(HH * 4));
    float* stats    = (float*)(w + alloc(256));
    size_t zero_end = off;
    int* nnz   = (int*)(w + alloc(NN * 4));
    int* colsI = (int*)(w + alloc((size_t)NN * MAXNBR * 4));
    float* dis = (float*)(w + alloc(NN * 4));
    unsigned short* xh  = (unsigned short*)(w + alloc((size_t)NN * FF * 2));
    unsigned short* xl  = (unsigned short*)(w + alloc((size_t)NN * FF * 2));
    unsigned short* W0h = (unsigned short*)(w + alloc((size_t)HH * FF * 2));
    unsigned short* W0l = (unsigned short*)(w + alloc((size_t)HH * FF * 2));
    unsigned short* W1h = (unsigned short*)(w + alloc((size_t)HH * HH * 2));
    unsigned short* W1l = (unsigned short*)(w + alloc((size_t)HH * HH * 2));
    unsigned short* W2h = (unsigned short*)(w + alloc((size_t)CC * HH * 2));
    unsigned short* W2l = (unsigned short*)(w + alloc((size_t)CC * HH * 2));
    unsigned short* hAh = (unsigned short*)(w + alloc((size_t)NN * HH * 2));
    unsigned short* hAl = (unsigned short*)(w + alloc((size_t)NN * HH * 2));
    float* hB   = (float*)(w + alloc((size_t)NN * HH * 4));
    float* hAgg = (float*)(w + alloc((size_t)NN * HH * 4));
    unsigned short* hBh = (unsigned short*)(w + alloc((size_t)NN * HH * 2));
    unsigned short* hBl = (unsigned short*)(w + alloc((size_t)NN * HH * 2));
    float* h3   = (float*)(w + alloc((size_t)NN * CC * 4));
    (void)ws_size; (void)in_sizes; (void)n_in; (void)out_size;

    hipMemsetAsync(d_ws, 0, zero_end, stream);

    // threshold: 4 x 8-bit histogram passes, each carrying 2048 deg blocks
    // (ALL 8192 adjacency rows processed here -> gemm kernels are pure)
    for (int p = 0; p < 4; ++p)
        hist8_kernel<<<256 + 2048, 256, 0, stream>>>(S0, S1, S2, hists, p,
                                                     adj, nnz, colsI, dis, p * 2048);

    // fused: masked weights -> hi/lo bf16  AND  x -> hi/lo bf16
    mask_split_fused<<<MASKB + NN * FF / 4 / 256, 256, 0, stream>>>(
        W0, W1, W2, S0, S1, S2, hists, W0h, W0l, W1h, W1l, W2h, W2l, x, xh, xl);

    // pure double-buffered gemms
    gemm_hl<64, 128, 1><<<(NN / 64) * (HH / 128), 256, 0, stream>>>(
        xh, xl, W0h, W0l, nullptr, hAh, hAl, HH, HH / 128);
    gemm_hl<64, 128, 0><<<(NN / 64) * (HH / 128), 256, 0, stream>>>(
        hAh, hAl, W1h, W1l, hB, nullptr, nullptr, HH, HH / 128);

    // aggregation
    spmm512<<<NN, 128, 0, stream>>>(nnz, colsI, dis, hB, hAgg);

    // pairnorm stats (single fused pass) + apply+relu -> hi/lo bf16
    colstats_kernel<<<256, 256, 0, stream>>>(hAgg, colsum, stats);
    pn_apply_split<<<(NN * HH / 4) / 256, 256, 0, stream>>>(hAgg, colsum, stats, hBh, hBl);

    // h3 = hB @ Wm2^T ; out = adj_n @ h3
    gemm_hl<32, 64, 0><<<(NN / 32) * (CC / 64), 256, 0, stream>>>(
        hBh, hBl, W2h, W2l, h3, nullptr, nullptr, CC, CC / 64);
    spmm64<<<NN, 64, 0, stream>>>(nnz, colsI, dis, h3, out);
}